// Round 7
// baseline (185.366 us; speedup 1.0000x reference)
//
#include <hip/hip_runtime.h>
#include <hip/hip_bf16.h>
#include <math.h>

#define B 2
#define N 2048
#define D 1024
#define H 16
#define HD 64

typedef __attribute__((ext_vector_type(8))) short short8;
typedef __attribute__((ext_vector_type(4))) float f32x4;
typedef __attribute__((ext_vector_type(16))) float f32x16;
typedef __attribute__((ext_vector_type(4))) unsigned short ush4;
typedef __attribute__((ext_vector_type(4))) unsigned int uint4v;

__device__ __forceinline__ float bf2f(unsigned short u) {
  unsigned int x = ((unsigned int)u) << 16;
  float f;
  __builtin_memcpy(&f, &x, 4);
  return f;
}
__device__ __forceinline__ unsigned short f2bf(float f) {
  unsigned int x;
  __builtin_memcpy(&x, &f, 4);
  x = x + 0x7fffu + ((x >> 16) & 1u);
  return (unsigned short)(x >> 16);
}
__device__ __forceinline__ unsigned int pk2(float lo, float hi) {
  union { __hip_bfloat162 h; unsigned int u; } cv;
  cv.h = __float22bfloat162_rn(make_float2(lo, hi));
  return cv.u;
}
__device__ __forceinline__ short8 mk_frag(unsigned int w0, unsigned int w1,
                                          unsigned int w2, unsigned int w3) {
  union { uint4v u; short8 s; } cv;
  cv.u = (uint4v){w0, w1, w2, w3};
  return cv.s;
}

// async global->LDS, 16B per lane (GEMM staging only).
__device__ __forceinline__ void gload16(const unsigned short* g, unsigned short* l) {
  __builtin_amdgcn_global_load_lds(
      (const __attribute__((address_space(1))) unsigned int*)(const void*)g,
      (__attribute__((address_space(3))) unsigned int*)(void*)l, 16, 0, 0);
}

// ---------- prep: weight conversions + rope tables in ONE launch ----------
__global__ void prep_k(const float* __restrict__ wqkv, unsigned short* __restrict__ wqkv_bf,
                       const float* __restrict__ wout, unsigned short* __restrict__ wout_bf,
                       float2* __restrict__ tab, float2* __restrict__ tabT) {
  int blk = blockIdx.x;
  if (blk < 4096) {
    const float* src = (blk < 3072) ? wqkv : wout;
    unsigned short* dst = (blk < 3072) ? wqkv_bf : wout_bf;
    int i = (blk < 3072 ? blk : blk - 3072) * 256 + threadIdx.x;
    float4 v = ((const float4*)src)[i];
    ush4 o;
    o[0] = f2bf(v.x); o[1] = f2bf(v.y); o[2] = f2bf(v.z); o[3] = f2bf(v.w);
    *(ush4*)&dst[i * 4] = o;
  } else {
    int idx = (blk - 4096) * 256 + threadIdx.x;  // 2048*32
    int t = idx >> 5, p = idx & 31;
    float inv = powf(10000.f, -(float)p / 32.f);
    float ang = (float)t * inv;
    float s, c;
    sincosf(ang, &s, &c);
    tab[idx] = make_float2(c, s);        // [t][p] for K-rope
    tabT[p * 2048 + t] = make_float2(c, s);  // [p][t] for Q-rope
  }
}

// x (B, D, N) f32 -> xt (B, N, D) bf16
__global__ __launch_bounds__(256) void transpose_x(const float* __restrict__ x,
                                                   unsigned short* __restrict__ xt) {
  __shared__ float tile[32][33];
  const int tx = threadIdx.x, ty = threadIdx.y;
  const int t0 = blockIdx.x * 32, d0 = blockIdx.y * 32, bb = blockIdx.z;
#pragma unroll
  for (int i = 0; i < 4; ++i) {
    int r = ty * 4 + i;
    tile[r][tx] = x[(size_t)bb * D * N + (size_t)(d0 + r) * N + t0 + tx];
  }
  __syncthreads();
#pragma unroll
  for (int i = 0; i < 4; ++i) {
    int r = ty * 4 + i;
    xt[((size_t)(bb * N) + t0 + r) * D + d0 + tx] = f2bf(tile[tx][r]);
  }
}

// ---------- GEMM: C[m][n] = sum_k A[m][k] * Bt[n][k], both K-contiguous bf16 ----------
// MODE 0: qkv projection. Q (n0<1024) -> q_em e-major (B,1024,N) vectorized;
//         K (1024<=n0<2048) -> kbuf token-major (B,N,1024) scalar;
//         V (n0>=2048)      -> vtbuf d-major (B,1024,N) vectorized.
// MODE 1: final projection -> f32 out (B, D, N).
template <int MODE>
__global__ __launch_bounds__(256) void gemm_bt(const unsigned short* __restrict__ A,
                                               const unsigned short* __restrict__ Bt,
                                               float* __restrict__ outf,
                                               unsigned short* __restrict__ q_em,
                                               unsigned short* __restrict__ kbuf,
                                               unsigned short* __restrict__ vtbuf) {
  __shared__ unsigned short Asm[128 * 64];
  __shared__ unsigned short Bsm[128 * 64];
  const int tid = threadIdx.x;
  const int lane = tid & 63, wid = tid >> 6;
  const int ln = lane & 15, lh = lane >> 4;
  const int wr = wid >> 1, wc = wid & 1;
  const int m0 = blockIdx.x * 128, n0 = blockIdx.y * 128;

  f32x4 acc[4][4];
#pragma unroll
  for (int i = 0; i < 4; ++i)
#pragma unroll
    for (int j = 0; j < 4; ++j) acc[i][j] = (f32x4){0.f, 0.f, 0.f, 0.f};

  for (int k0 = 0; k0 < 1024; k0 += 64) {
#pragma unroll
    for (int jj = 0; jj < 4; ++jj) {
      int slot = tid + jj * 256;
      int row = slot >> 3, u = slot & 7;
      int usw = (u ^ (row & 7)) * 8;
      gload16(&A[(size_t)(m0 + row) * 1024 + k0 + usw], &Asm[slot * 8]);
    }
#pragma unroll
    for (int jj = 0; jj < 4; ++jj) {
      int slot = tid + jj * 256;
      int row = slot >> 3, u = slot & 7;
      int usw = (u ^ (row & 7)) * 8;
      gload16(&Bt[(size_t)(n0 + row) * 1024 + k0 + usw], &Bsm[slot * 8]);
    }
    __syncthreads();
#pragma unroll
    for (int s = 0; s < 2; ++s) {
      short8 af[4], bfr[4];
#pragma unroll
      for (int i = 0; i < 4; ++i) {
        int row = wr * 64 + i * 16 + ln;
        int u = ((s * 4 + lh) ^ (row & 7)) * 8;
        af[i] = *(const short8*)&Asm[row * 64 + u];
      }
#pragma unroll
      for (int j = 0; j < 4; ++j) {
        int row = wc * 64 + j * 16 + ln;
        int u = ((s * 4 + lh) ^ (row & 7)) * 8;
        bfr[j] = *(const short8*)&Bsm[row * 64 + u];
      }
#pragma unroll
      for (int i = 0; i < 4; ++i)
#pragma unroll
        for (int j = 0; j < 4; ++j)
          acc[i][j] = __builtin_amdgcn_mfma_f32_16x16x32_bf16(af[i], bfr[j], acc[i][j], 0, 0, 0);
    }
    __syncthreads();
  }

#pragma unroll
  for (int i = 0; i < 4; ++i) {
    int mrow = m0 + wr * 64 + i * 16 + lh * 4;
    int bb = mrow >> 11, t = mrow & 2047;
#pragma unroll
    for (int j = 0; j < 4; ++j) {
      int e = n0 + wc * 64 + j * 16 + ln;
      if (MODE == 1) {
        float* op = outf + (size_t)bb * D * N + (size_t)e * N + t;
        *(f32x4*)op = acc[i][j];
      } else {
        ush4 v;
#pragma unroll
        for (int jj = 0; jj < 4; ++jj) v[jj] = f2bf(acc[i][j][jj]);
        if (e < 1024) {
          // Q e-major: 4 consecutive t -> one 8B store
          *(ush4*)&q_em[((size_t)bb * 1024 + e) * N + t] = v;
        } else if (e < 2048) {
          // K token-major: scalar stores (attn stages K per tile)
#pragma unroll
          for (int jj = 0; jj < 4; ++jj)
            kbuf[((size_t)(bb * N + t + jj)) * 1024 + (e - 1024)] = v[jj];
        } else {
          *(ush4*)&vtbuf[((size_t)bb * 1024 + (e - 2048)) * N + t] = v;
        }
      }
    }
  }
}

// ---------- RoPE: Q (e-major, folds 0.125*log2e) + K (token-major) ----------
// blocks [0,1024): Q rows; blocks [1024,3072): K tokens.
__global__ void rope2_kernel(unsigned short* __restrict__ q_em,
                             unsigned short* __restrict__ kbuf,
                             const float2* __restrict__ tab,
                             const float2* __restrict__ tabT) {
  const float qscl = 0.125f * 1.4426950408889634f;
  int blk = blockIdx.x;
  if (blk < 1024) {
    // Q: idx over (b, h, p, t8): pair rows 2p,2p+1 (stride N), 8 tokens each
    int idx = blk * 256 + threadIdx.x;          // [0, 262144)
    int t0 = (idx & 255) * 8;
    int pr = idx >> 8;                          // [0, 1024)
    int p = pr & 31, h = (pr >> 5) & 15, bb = pr >> 9;
    unsigned short* re = q_em + ((size_t)bb * 1024 + h * 64 + 2 * p) * N + t0;
    unsigned short* ro = re + N;
    short8 ve = *(short8*)re, vo = *(short8*)ro;
    const float2* ct = &tabT[p * 2048 + t0];
#pragma unroll
    for (int i = 0; i < 8; ++i) {
      float2 cs = ct[i];
      float xe = bf2f((unsigned short)ve[i]);
      float xo = bf2f((unsigned short)vo[i]);
      ve[i] = (short)f2bf((xe * cs.x - xo * cs.y) * qscl);
      vo[i] = (short)f2bf((xe * cs.y + xo * cs.x) * qscl);
    }
    *(short8*)re = ve;
    *(short8*)ro = vo;
  } else {
    // K token-major (B, N, 1024), pairs adjacent
    int idx = (blk - 1024) * 256 + threadIdx.x;  // [0, 524288)
    int e = (idx & 127) * 8;
    int t = (idx >> 7) & 2047;
    int bb = idx >> 18;
    int p0 = (e & 63) >> 1;
    unsigned short* p = kbuf + ((size_t)(bb * N + t)) * 1024 + e;
    short8 v = *(short8*)p;
#pragma unroll
    for (int q = 0; q < 4; ++q) {
      float2 cs = tab[t * 32 + p0 + q];
      float xe = bf2f((unsigned short)v[2 * q]);
      float xo = bf2f((unsigned short)v[2 * q + 1]);
      v[2 * q] = (short)f2bf(xe * cs.x - xo * cs.y);
      v[2 * q + 1] = (short)f2bf(xe * cs.y + xo * cs.x);
    }
    *(short8*)p = v;
  }
}

// ---------- flash attention: swapped 32x32 MFMA, static-max, reg-staged K/V ----------
// T14: global->reg loads issued BEFORE compute, ds_write AFTER (latency hides
// under QK/exp/PV). 2 LDS buffers, manual x2 unroll for static indices.
// q_em: (B,1024,N); kbuf: (B,N,1024); vt: (B,1024,N); ob: (B,N,1024).
__global__ __launch_bounds__(512, 4) void attn_kernel(const unsigned short* __restrict__ q_em,
                                                      const unsigned short* __restrict__ kbuf,
                                                      const unsigned short* __restrict__ vt,
                                                      unsigned short* __restrict__ ob) {
  __shared__ __align__(16) char smem[66048];  // K bufs 32K | V bufs 32K | lbuf
  const int tid = threadIdx.x;
  const int lane = tid & 63, wid = tid >> 6;
  const int l31 = lane & 31, hi = lane >> 5;
  const int g = wid >> 2, wl = wid & 3;
  const int tidg = tid & 255;
  const int L = blockIdx.x;
  const int hh = L & 31, qb = L >> 5;
  const int bb = hh >> 4, h = hh & 15;
  const unsigned short* Qg = q_em + ((size_t)bb * 1024 + h * 64) * N;
  const unsigned short* Kg = kbuf + (size_t)bb * N * 1024 + h * 64;
  const unsigned short* Vg = vt + ((size_t)bb * 1024 + h * 64) * N;

  unsigned short* K0 = (unsigned short*)smem + (g * 2 + 0) * 4096;
  unsigned short* K1 = (unsigned short*)smem + (g * 2 + 1) * 4096;
  unsigned short* V0 = (unsigned short*)(smem + 32768) + (g * 2 + 0) * 4096;
  unsigned short* V1 = (unsigned short*)(smem + 32768) + (g * 2 + 1) * 4096;

  const int q = qb * 128 + wl * 32 + l31;
  // Q B-fragments from e-major: elements k(d) = c*16 + hi*8 + j at stride N
  short8 qf[4];
#pragma unroll
  for (int c = 0; c < 4; ++c) {
    short8 f;
#pragma unroll
    for (int j = 0; j < 8; ++j)
      f[j] = (short)Qg[(size_t)(c * 16 + hi * 8 + j) * N + q];
    qf[c] = f;
  }

  f32x16 oL, oH;
#pragma unroll
  for (int r = 0; r < 16; ++r) { oL[r] = 0.f; oH[r] = 0.f; }
  float lrun = 0.f;

  const int kb0 = g * 1024;
  const int row0 = tidg >> 3, u0 = tidg & 7;   // slot0; slot1 = row0+32, same u
  const int usw0 = (u0 ^ (row0 & 7)) * 8;
  const int usw1 = (u0 ^ ((row0 + 32) & 7)) * 8;
  uint4v kra, krb, vra, vrb;

  auto LOADNEXT = [&](int kb) {
    kra = *(const uint4v*)&Kg[(size_t)(kb + row0) * 1024 + u0 * 8];
    krb = *(const uint4v*)&Kg[(size_t)(kb + row0 + 32) * 1024 + u0 * 8];
    vra = *(const uint4v*)&Vg[(size_t)row0 * N + kb + u0 * 8];
    vrb = *(const uint4v*)&Vg[(size_t)(row0 + 32) * N + kb + u0 * 8];
  };
  auto WRITESTAGE = [&](unsigned short* Kb, unsigned short* Vb) {
    *(uint4v*)&Kb[row0 * 64 + usw0] = kra;
    *(uint4v*)&Kb[(row0 + 32) * 64 + usw1] = krb;
    *(uint4v*)&Vb[row0 * 64 + usw0] = vra;
    *(uint4v*)&Vb[(row0 + 32) * 64 + usw1] = vrb;
  };
  auto COMPUTE = [&](const unsigned short* Kb, const unsigned short* Vb) {
    f32x16 s0, s1;
#pragma unroll
    for (int r = 0; r < 16; ++r) { s0[r] = 0.f; s1[r] = 0.f; }
    __builtin_amdgcn_s_setprio(1);
#pragma unroll
    for (int c = 0; c < 4; ++c) {
      short8 ka = *(const short8*)&Kb[l31 * 64 + (((c * 2 + hi) ^ (l31 & 7)) * 8)];
      s0 = __builtin_amdgcn_mfma_f32_32x32x16_bf16(ka, qf[c], s0, 0, 0, 0);
      int r1 = 32 + l31;
      short8 kb2 = *(const short8*)&Kb[r1 * 64 + (((c * 2 + hi) ^ (r1 & 7)) * 8)];
      s1 = __builtin_amdgcn_mfma_f32_32x32x16_bf16(kb2, qf[c], s1, 0, 0, 0);
    }
    __builtin_amdgcn_s_setprio(0);
    float lsum = 0.f;
#pragma unroll
    for (int r = 0; r < 16; ++r) {
      s0[r] = __builtin_amdgcn_exp2f(s0[r]);
      s1[r] = __builtin_amdgcn_exp2f(s1[r]);
      lsum += s0[r] + s1[r];
    }
    lrun += lsum;
    unsigned int W[16];
#pragma unroll
    for (int i = 0; i < 8; ++i) {
      W[i] = pk2(s0[2 * i], s0[2 * i + 1]);
      W[8 + i] = pk2(s1[2 * i], s1[2 * i + 1]);
    }
    short8 pf[4];
#pragma unroll
    for (int c = 0; c < 4; ++c) {
      unsigned int a0 = W[4 * c + 0], b0 = W[4 * c + 2];
      unsigned int a1 = W[4 * c + 1], b1 = W[4 * c + 3];
      asm volatile("v_permlane32_swap_b32 %0, %1" : "+v"(a0), "+v"(b0));
      asm volatile("v_permlane32_swap_b32 %0, %1" : "+v"(a1), "+v"(b1));
      pf[c] = mk_frag(a0, a1, b0, b1);
    }
    __builtin_amdgcn_s_setprio(1);
#pragma unroll
    for (int c = 0; c < 4; ++c) {
      short8 va = *(const short8*)&Vb[l31 * 64 + (((c * 2 + hi) ^ (l31 & 7)) * 8)];
      oL = __builtin_amdgcn_mfma_f32_32x32x16_bf16(va, pf[c], oL, 0, 0, 0);
      int rH = 32 + l31;
      short8 vb = *(const short8*)&Vb[rH * 64 + (((c * 2 + hi) ^ (rH & 7)) * 8)];
      oH = __builtin_amdgcn_mfma_f32_32x32x16_bf16(vb, pf[c], oH, 0, 0, 0);
    }
    __builtin_amdgcn_s_setprio(0);
  };

  // prologue: stage tile 0 into buf0
  LOADNEXT(kb0);
  WRITESTAGE(K0, V0);
  __syncthreads();
  for (int tt = 0; tt < 16; tt += 2) {
    // even: compute buf0, prefetch tile tt+1 -> buf1
    LOADNEXT(kb0 + (tt + 1) * 64);
    COMPUTE(K0, V0);
    WRITESTAGE(K1, V1);   // compiler inserts vmcnt wait here (loads landed)
    __syncthreads();
    // odd: compute buf1, prefetch tile tt+2 -> buf0
    if (tt + 2 < 16) LOADNEXT(kb0 + (tt + 2) * 64);
    COMPUTE(K1, V1);
    if (tt + 2 < 16) WRITESTAGE(K0, V0);
    __syncthreads();
  }
  lrun += __shfl_xor(lrun, 32, 64);

  // combine the two key-halves through LDS (plain add: static max)
  float* cmb = (float*)smem;
  float* lbuf = (float*)(smem + 65536);
  const int ql = wl * 32 + l31;
  if (g) {
#pragma unroll
    for (int r4 = 0; r4 < 4; ++r4) {
      int bo = (ql * 256 + r4 * 32 + hi * 16) ^ ((ql & 7) << 4);
      *(f32x4*)((char*)cmb + bo) =
          (f32x4){oL[r4 * 4], oL[r4 * 4 + 1], oL[r4 * 4 + 2], oL[r4 * 4 + 3]};
      int bo2 = (ql * 256 + 128 + r4 * 32 + hi * 16) ^ ((ql & 7) << 4);
      *(f32x4*)((char*)cmb + bo2) =
          (f32x4){oH[r4 * 4], oH[r4 * 4 + 1], oH[r4 * 4 + 2], oH[r4 * 4 + 3]};
    }
    if (!hi) lbuf[ql] = lrun;
  }
  __syncthreads();
  if (!g) {
#pragma unroll
    for (int r4 = 0; r4 < 4; ++r4) {
      int bo = (ql * 256 + r4 * 32 + hi * 16) ^ ((ql & 7) << 4);
      f32x4 pL = *(const f32x4*)((const char*)cmb + bo);
      int bo2 = (ql * 256 + 128 + r4 * 32 + hi * 16) ^ ((ql & 7) << 4);
      f32x4 pH = *(const f32x4*)((const char*)cmb + bo2);
#pragma unroll
      for (int i = 0; i < 4; ++i) {
        oL[r4 * 4 + i] += pL[i];
        oH[r4 * 4 + i] += pH[i];
      }
    }
    lrun += lbuf[ql];
    float inv = 1.f / lrun;
    unsigned short* obp = ob + ((size_t)(bb * N + q)) * 1024 + h * 64;
#pragma unroll
    for (int r4 = 0; r4 < 4; ++r4) {
      ush4 vL, vH;
#pragma unroll
      for (int i = 0; i < 4; ++i) {
        vL[i] = f2bf(oL[r4 * 4 + i] * inv);
        vH[i] = f2bf(oH[r4 * 4 + i] * inv);
      }
      *(ush4*)&obp[r4 * 8 + hi * 4] = vL;
      *(ush4*)&obp[32 + r4 * 8 + hi * 4] = vH;
    }
  }
}

extern "C" void kernel_launch(void* const* d_in, const int* in_sizes, int n_in,
                              void* d_out, int out_size, void* d_ws, size_t ws_size,
                              hipStream_t stream) {
  const float* x = (const float*)d_in[0];
  const float* w_qkv = (const float*)d_in[1];
  const float* w_out = (const float*)d_in[2];
  float* out = (float*)d_out;
  char* ws = (char*)d_ws;

  unsigned short* wqkv_bf = (unsigned short*)ws;                    // 6 MB
  unsigned short* wout_bf = (unsigned short*)(ws + 6291456);        // 2 MB
  unsigned short* xt      = (unsigned short*)(ws + 8388608);        // 8 MB (reused as obuf)
  unsigned short* q_em    = (unsigned short*)(ws + 16777216);       // 8 MB
  unsigned short* kbuf    = (unsigned short*)(ws + 25165824);       // 8 MB
  unsigned short* vtbuf   = (unsigned short*)(ws + 33554432);       // 8 MB
  float2* tab             = (float2*)(ws + 41943040);               // 512 KB
  float2* tabT            = (float2*)(ws + 42467328);               // 512 KB

  prep_k<<<4352, 256, 0, stream>>>(w_qkv, wqkv_bf, w_out, wout_bf, tab, tabT);
  transpose_x<<<dim3(N / 32, D / 32, B), dim3(32, 8), 0, stream>>>(x, xt);

  gemm_bt<0><<<dim3(32, 24), 256, 0, stream>>>(xt, wqkv_bf, nullptr, q_em, kbuf, vtbuf);
  rope2_kernel<<<3072, 256, 0, stream>>>(q_em, kbuf, tab, tabT);
  attn_kernel<<<512, 512, 0, stream>>>(q_em, kbuf, vtbuf, xt /* obuf */);
  gemm_bt<1><<<dim3(32, 8), 256, 0, stream>>>(xt, wout_bf, out, nullptr, nullptr, nullptr);
}

// Round 8
// 127.644 us; speedup vs baseline: 1.4522x; 1.4522x over previous
//
#include <hip/hip_runtime.h>
#include <hip/hip_bf16.h>
#include <math.h>

#define B 2
#define N 2048
#define D 1024
#define H 16
#define HD 64

typedef __attribute__((ext_vector_type(8))) short short8;
typedef __attribute__((ext_vector_type(4))) float f32x4;
typedef __attribute__((ext_vector_type(16))) float f32x16;
typedef __attribute__((ext_vector_type(4))) unsigned short ush4;
typedef __attribute__((ext_vector_type(4))) unsigned int uint4v;

__device__ __forceinline__ float bf2f(unsigned short u) {
  unsigned int x = ((unsigned int)u) << 16;
  float f;
  __builtin_memcpy(&f, &x, 4);
  return f;
}
__device__ __forceinline__ unsigned short f2bf(float f) {
  unsigned int x;
  __builtin_memcpy(&x, &f, 4);
  x = x + 0x7fffu + ((x >> 16) & 1u);
  return (unsigned short)(x >> 16);
}
__device__ __forceinline__ unsigned int pk2(float lo, float hi) {
  union { __hip_bfloat162 h; unsigned int u; } cv;
  cv.h = __float22bfloat162_rn(make_float2(lo, hi));
  return cv.u;
}
__device__ __forceinline__ short8 mk_frag(unsigned int w0, unsigned int w1,
                                          unsigned int w2, unsigned int w3) {
  union { uint4v u; short8 s; } cv;
  cv.u = (uint4v){w0, w1, w2, w3};
  return cv.s;
}

// async global->LDS, 16B per lane. LDS dest linear (base + lane*16);
// swizzle lives in the per-lane GLOBAL address (m173/m201 pattern).
__device__ __forceinline__ void gload16(const unsigned short* g, unsigned short* l) {
  __builtin_amdgcn_global_load_lds(
      (const __attribute__((address_space(1))) unsigned int*)(const void*)g,
      (__attribute__((address_space(3))) unsigned int*)(void*)l, 16, 0, 0);
}

// ---------- prep: weight conversions + rope table in ONE launch ----------
__global__ void prep_k(const float* __restrict__ wqkv, unsigned short* __restrict__ wqkv_bf,
                       const float* __restrict__ wout, unsigned short* __restrict__ wout_bf,
                       float2* __restrict__ tab) {
  int blk = blockIdx.x;
  if (blk < 4096) {
    const float* src = (blk < 3072) ? wqkv : wout;
    unsigned short* dst = (blk < 3072) ? wqkv_bf : wout_bf;
    int i = (blk < 3072 ? blk : blk - 3072) * 256 + threadIdx.x;
    float4 v = ((const float4*)src)[i];
    ush4 o;
    o[0] = f2bf(v.x); o[1] = f2bf(v.y); o[2] = f2bf(v.z); o[3] = f2bf(v.w);
    *(ush4*)&dst[i * 4] = o;
  } else {
    int idx = (blk - 4096) * 256 + threadIdx.x;  // 2048*32
    int t = idx >> 5, p = idx & 31;
    float inv = powf(10000.f, -(float)p / 32.f);
    float ang = (float)t * inv;
    float s, c;
    sincosf(ang, &s, &c);
    tab[idx] = make_float2(c, s);
  }
}

// x (B, D, N) f32 -> xt (B, N, D) bf16
__global__ __launch_bounds__(256) void transpose_x(const float* __restrict__ x,
                                                   unsigned short* __restrict__ xt) {
  __shared__ float tile[32][33];
  const int tx = threadIdx.x, ty = threadIdx.y;
  const int t0 = blockIdx.x * 32, d0 = blockIdx.y * 32, bb = blockIdx.z;
#pragma unroll
  for (int i = 0; i < 4; ++i) {
    int r = ty * 4 + i;
    tile[r][tx] = x[(size_t)bb * D * N + (size_t)(d0 + r) * N + t0 + tx];
  }
  __syncthreads();
#pragma unroll
  for (int i = 0; i < 4; ++i) {
    int r = ty * 4 + i;
    xt[((size_t)(bb * N) + t0 + r) * D + d0 + tx] = f2bf(tile[tx][r]);
  }
}

// ---------- GEMM: C[m][n] = sum_k A[m][k] * Bt[n][k], both K-contiguous bf16 ----------
// 128x128 tile, BK=64, 4 waves (2x2), wave = 64x64 (4x4 fragments of 16x16x32).
// MODE 0: qkv projection epilogue -> q/k token-major into qkbuf, v transposed into vtbuf.
// MODE 1: final projection epilogue -> f32 out (B, D, N).
template <int MODE>
__global__ __launch_bounds__(256) void gemm_bt(const unsigned short* __restrict__ A,
                                               const unsigned short* __restrict__ Bt,
                                               float* __restrict__ outf,
                                               unsigned short* __restrict__ qkbuf,
                                               unsigned short* __restrict__ vtbuf) {
  __shared__ unsigned short Asm[128 * 64];
  __shared__ unsigned short Bsm[128 * 64];
  const int tid = threadIdx.x;
  const int lane = tid & 63, wid = tid >> 6;
  const int ln = lane & 15, lh = lane >> 4;
  const int wr = wid >> 1, wc = wid & 1;
  const int m0 = blockIdx.x * 128, n0 = blockIdx.y * 128;

  f32x4 acc[4][4];
#pragma unroll
  for (int i = 0; i < 4; ++i)
#pragma unroll
    for (int j = 0; j < 4; ++j) acc[i][j] = (f32x4){0.f, 0.f, 0.f, 0.f};

  for (int k0 = 0; k0 < 1024; k0 += 64) {
#pragma unroll
    for (int jj = 0; jj < 4; ++jj) {
      int slot = tid + jj * 256;
      int row = slot >> 3, u = slot & 7;
      int usw = (u ^ (row & 7)) * 8;
      gload16(&A[(size_t)(m0 + row) * 1024 + k0 + usw], &Asm[slot * 8]);
    }
#pragma unroll
    for (int jj = 0; jj < 4; ++jj) {
      int slot = tid + jj * 256;
      int row = slot >> 3, u = slot & 7;
      int usw = (u ^ (row & 7)) * 8;
      gload16(&Bt[(size_t)(n0 + row) * 1024 + k0 + usw], &Bsm[slot * 8]);
    }
    __syncthreads();
#pragma unroll
    for (int s = 0; s < 2; ++s) {
      short8 af[4], bfr[4];
#pragma unroll
      for (int i = 0; i < 4; ++i) {
        int row = wr * 64 + i * 16 + ln;
        int u = ((s * 4 + lh) ^ (row & 7)) * 8;
        af[i] = *(const short8*)&Asm[row * 64 + u];
      }
#pragma unroll
      for (int j = 0; j < 4; ++j) {
        int row = wc * 64 + j * 16 + ln;
        int u = ((s * 4 + lh) ^ (row & 7)) * 8;
        bfr[j] = *(const short8*)&Bsm[row * 64 + u];
      }
#pragma unroll
      for (int i = 0; i < 4; ++i)
#pragma unroll
        for (int j = 0; j < 4; ++j)
          acc[i][j] = __builtin_amdgcn_mfma_f32_16x16x32_bf16(af[i], bfr[j], acc[i][j], 0, 0, 0);
    }
    __syncthreads();
  }

#pragma unroll
  for (int i = 0; i < 4; ++i) {
    int mrow = m0 + wr * 64 + i * 16 + lh * 4;
    int bb = mrow >> 11, t = mrow & 2047;
#pragma unroll
    for (int j = 0; j < 4; ++j) {
      int e = n0 + wc * 64 + j * 16 + ln;
      if (MODE == 1) {
        float* op = outf + (size_t)bb * D * N + (size_t)e * N + t;
        *(f32x4*)op = acc[i][j];
      } else {
        if (e < 2048) {
#pragma unroll
          for (int jj = 0; jj < 4; ++jj)
            qkbuf[((size_t)(bb * N + t + jj)) * 2048 + e] = f2bf(acc[i][j][jj]);
        } else {
          ush4 v;
#pragma unroll
          for (int jj = 0; jj < 4; ++jj) v[jj] = f2bf(acc[i][j][jj]);
          *(ush4*)&vtbuf[((size_t)bb * 1024 + (e - 2048)) * N + t] = v;
        }
      }
    }
  }
}

// ---------- RoPE in place on qkbuf (B, N, 2048) bf16, pairs adjacent ----------
// Folds 0.125*log2e into the q section so attention uses exp2 with no scaling.
__global__ void rope_kernel(unsigned short* __restrict__ qk, const float2* __restrict__ tab) {
  int idx = blockIdx.x * 256 + threadIdx.x;  // B*N*2048/8 = 1,048,576
  int e = (idx & 255) * 8;
  int t = (idx >> 8) & 2047;
  int bb = idx >> 19;
  int p0 = (e & 63) >> 1;
  const float qscl = 0.125f * 1.4426950408889634f;  // hd^-0.5 * log2(e)
  float sc = (e < 1024) ? qscl : 1.0f;
  unsigned short* p = qk + ((size_t)(bb * N + t)) * 2048 + e;
  short8 v = *(short8*)p;
#pragma unroll
  for (int q = 0; q < 4; ++q) {
    float2 cs = tab[t * 32 + p0 + q];
    float xe = bf2f((unsigned short)v[2 * q]);
    float xo = bf2f((unsigned short)v[2 * q + 1]);
    v[2 * q] = (short)f2bf((xe * cs.x - xo * cs.y) * sc);
    v[2 * q + 1] = (short)f2bf((xe * cs.y + xo * cs.x) * sc);
  }
  *(short8*)p = v;
}

// ---------- flash attention: swapped 32x32 MFMA, static-max, 3-buf counted-vmcnt ----------
// T3/T4: 3-deep LDS ring, 2 raw barriers/iter, vmcnt(8) = 4 loads/tile x 2 tiles
// in flight (m201 formula). Tile t+2's loads get 2 compute phases to land.
// Hazards: barrier1 (after all waves' COMPUTE(t-1)) protects STAGE overwrite of
// b[(t-1)%3]; per-wave vmcnt(8) before barrier2 publishes tile t.
// qk: (B, N, 2048) bf16 (q pre-scaled by 0.125*log2e); vt: (B, 1024, N) bf16.
__global__ __launch_bounds__(256, 2) void attn_kernel(const unsigned short* __restrict__ qk,
                                                      const unsigned short* __restrict__ vt,
                                                      unsigned short* __restrict__ ob) {
  __shared__ unsigned short Ksm[3][64 * 64];  // [key][d] swizzled
  __shared__ unsigned short Vsm[3][64 * 64];  // [d][key] swizzled
  const int tid = threadIdx.x;
  const int lane = tid & 63, wid = tid >> 6;
  const int l31 = lane & 31, hi = lane >> 5;
  const int L = blockIdx.x;
  const int hh = L & 31, qb = L >> 5;
  const int bb = hh >> 4, h = hh & 15;
  const unsigned short* Qg = qk + (size_t)bb * N * 2048 + h * 64;
  const unsigned short* Kg = Qg + 1024;
  const unsigned short* Vg = vt + ((size_t)bb * 1024 + h * 64) * N;

  const int q = qb * 128 + wid * 32 + l31;
  // Q as B-fragments: lane holds q-col, k(d) = c*16 + hi*8 + j
  short8 qf[4];
#pragma unroll
  for (int c = 0; c < 4; ++c)
    qf[c] = *(const short8*)&Qg[(size_t)q * 2048 + c * 16 + hi * 8];

  f32x16 oL, oH;
#pragma unroll
  for (int r = 0; r < 16; ++r) { oL[r] = 0.f; oH[r] = 0.f; }
  float lrun = 0.f;

  auto STAGE = [&](unsigned short* Kb, unsigned short* Vb, int kb) {
#pragma unroll
    for (int jj = 0; jj < 2; ++jj) {
      int slot = tid + jj * 256;
      int row = slot >> 3, u = slot & 7;
      int usw = (u ^ (row & 7)) * 8;
      gload16(&Kg[(size_t)(kb + row) * 2048 + usw], &Kb[slot * 8]);
    }
#pragma unroll
    for (int jj = 0; jj < 2; ++jj) {
      int slot = tid + jj * 256;
      int row = slot >> 3, u = slot & 7;
      int usw = (u ^ (row & 7)) * 8;
      gload16(&Vg[(size_t)row * N + kb + usw], &Vb[slot * 8]);
    }
  };

  auto COMPUTE = [&](const unsigned short* Kb, const unsigned short* Vb) {
    f32x16 s0, s1;
#pragma unroll
    for (int r = 0; r < 16; ++r) { s0[r] = 0.f; s1[r] = 0.f; }
    __builtin_amdgcn_s_setprio(1);
#pragma unroll
    for (int c = 0; c < 4; ++c) {
      short8 ka = *(const short8*)&Kb[l31 * 64 + (((c * 2 + hi) ^ (l31 & 7)) * 8)];
      s0 = __builtin_amdgcn_mfma_f32_32x32x16_bf16(ka, qf[c], s0, 0, 0, 0);
      int r1 = 32 + l31;
      short8 kb2 = *(const short8*)&Kb[r1 * 64 + (((c * 2 + hi) ^ (r1 & 7)) * 8)];
      s1 = __builtin_amdgcn_mfma_f32_32x32x16_bf16(kb2, qf[c], s1, 0, 0, 0);
    }
    __builtin_amdgcn_s_setprio(0);
    float lsum = 0.f;
#pragma unroll
    for (int r = 0; r < 16; ++r) {
      s0[r] = __builtin_amdgcn_exp2f(s0[r]);
      s1[r] = __builtin_amdgcn_exp2f(s1[r]);
      lsum += s0[r] + s1[r];
    }
    lrun += lsum;
    unsigned int W[16];
#pragma unroll
    for (int i = 0; i < 8; ++i) {
      W[i] = pk2(s0[2 * i], s0[2 * i + 1]);
      W[8 + i] = pk2(s1[2 * i], s1[2 * i + 1]);
    }
    short8 pf[4];
#pragma unroll
    for (int c = 0; c < 4; ++c) {
      unsigned int a0 = W[4 * c + 0], b0 = W[4 * c + 2];
      unsigned int a1 = W[4 * c + 1], b1 = W[4 * c + 3];
      asm volatile("v_permlane32_swap_b32 %0, %1" : "+v"(a0), "+v"(b0));
      asm volatile("v_permlane32_swap_b32 %0, %1" : "+v"(a1), "+v"(b1));
      pf[c] = mk_frag(a0, a1, b0, b1);
    }
    __builtin_amdgcn_s_setprio(1);
#pragma unroll
    for (int c = 0; c < 4; ++c) {
      short8 va = *(const short8*)&Vb[l31 * 64 + (((c * 2 + hi) ^ (l31 & 7)) * 8)];
      oL = __builtin_amdgcn_mfma_f32_32x32x16_bf16(va, pf[c], oL, 0, 0, 0);
      int rH = 32 + l31;
      short8 vb = *(const short8*)&Vb[rH * 64 + (((c * 2 + hi) ^ (rH & 7)) * 8)];
      oH = __builtin_amdgcn_mfma_f32_32x32x16_bf16(vb, pf[c], oH, 0, 0, 0);
    }
    __builtin_amdgcn_s_setprio(0);
  };

  // one pipelined iteration: barrier1 | STAGE(t+2) | vmcnt(8) | barrier2 | COMPUTE(t)
  auto ITER = [&](int t, int bc, int bn) {
    __builtin_amdgcn_s_barrier();                       // all waves done COMPUTE(t-1)
    STAGE(Ksm[bn], Vsm[bn], (t + 2) * 64);              // overwrite b[(t-1)%3]
    asm volatile("s_waitcnt vmcnt(8)" ::: "memory");    // my tile-t loads landed
    __builtin_amdgcn_sched_barrier(0);
    __builtin_amdgcn_s_barrier();                       // everyone's tile-t landed
    COMPUTE(Ksm[bc], Vsm[bc]);
  };

  STAGE(Ksm[0], Vsm[0], 0);
  STAGE(Ksm[1], Vsm[1], 64);
  for (int tt = 0; tt < 30; tt += 3) {
    ITER(tt + 0, 0, 2);
    ITER(tt + 1, 1, 0);
    ITER(tt + 2, 2, 1);
  }
  // t = 30: no stage; outstanding = t30(4) + t31(4) -> wait t30 via vmcnt(4)
  __builtin_amdgcn_s_barrier();
  asm volatile("s_waitcnt vmcnt(4)" ::: "memory");
  __builtin_amdgcn_sched_barrier(0);
  __builtin_amdgcn_s_barrier();
  COMPUTE(Ksm[0], Vsm[0]);
  // t = 31: drain my t31 loads, then barrier so everyone's are visible
  asm volatile("s_waitcnt vmcnt(0)" ::: "memory");
  __builtin_amdgcn_sched_barrier(0);
  __builtin_amdgcn_s_barrier();
  COMPUTE(Ksm[1], Vsm[1]);

  // final l reduce (partner lane holds the other 32 keys of every tile)
  lrun += __shfl_xor(lrun, 32, 64);
  float inv = 1.f / lrun;
  unsigned short* obp = ob + ((size_t)(bb * N + q)) * 1024 + h * 64;
#pragma unroll
  for (int r4 = 0; r4 < 4; ++r4) {
    ush4 vL, vH;
#pragma unroll
    for (int i = 0; i < 4; ++i) {
      vL[i] = f2bf(oL[r4 * 4 + i] * inv);
      vH[i] = f2bf(oH[r4 * 4 + i] * inv);
    }
    *(ush4*)&obp[r4 * 8 + hi * 4] = vL;
    *(ush4*)&obp[32 + r4 * 8 + hi * 4] = vH;
  }
}

extern "C" void kernel_launch(void* const* d_in, const int* in_sizes, int n_in,
                              void* d_out, int out_size, void* d_ws, size_t ws_size,
                              hipStream_t stream) {
  const float* x = (const float*)d_in[0];
  const float* w_qkv = (const float*)d_in[1];
  const float* w_out = (const float*)d_in[2];
  float* out = (float*)d_out;
  char* ws = (char*)d_ws;

  unsigned short* wqkv_bf = (unsigned short*)ws;                    // 6 MB
  unsigned short* wout_bf = (unsigned short*)(ws + 6291456);        // 2 MB
  unsigned short* xt      = (unsigned short*)(ws + 8388608);        // 8 MB (reused as obuf)
  unsigned short* qkbuf   = (unsigned short*)(ws + 16777216);       // 16 MB
  unsigned short* vtbuf   = (unsigned short*)(ws + 33554432);       // 8 MB
  float2* tab             = (float2*)(ws + 41943040);               // 0.5 MB

  prep_k<<<4352, 256, 0, stream>>>(w_qkv, wqkv_bf, w_out, wout_bf, tab);
  transpose_x<<<dim3(N / 32, D / 32, B), dim3(32, 8), 0, stream>>>(x, xt);

  gemm_bt<0><<<dim3(32, 24), 256, 0, stream>>>(xt, wqkv_bf, nullptr, qkbuf, vtbuf);
  rope_kernel<<<4096, 256, 0, stream>>>(qkbuf, tab);
  attn_kernel<<<512, 256, 0, stream>>>(qkbuf, vtbuf, xt /* obuf */);
  gemm_bt<1><<<dim3(32, 8), 256, 0, stream>>>(xt, wout_bf, out, nullptr, nullptr);
}